// Round 19
// baseline (593.001 us; speedup 1.0000x reference)
//
#include <hip/hip_runtime.h>

#define N_PTS 262144
#define NG 128
#define GS 1024
#define FPS_B 16

typedef __attribute__((ext_vector_type(8))) short short8;
typedef __attribute__((ext_vector_type(8))) __bf16 bf16x8;
typedef __attribute__((ext_vector_type(4))) float f32x4;
typedef unsigned long long ull;

__device__ __forceinline__ unsigned short f2bf(float f) {
  unsigned u = __float_as_uint(f);
  unsigned r = u + 0x7FFFu + ((u >> 16) & 1u);
  return (unsigned short)(r >> 16);
}

__device__ __forceinline__ f32x4 mfma16(short8 a, short8 b, f32x4 c) {
  return __builtin_amdgcn_mfma_f32_16x16x32_bf16(
      __builtin_bit_cast(bf16x8, a), __builtin_bit_cast(bf16x8, b), c, 0, 0, 0);
}

__device__ __forceinline__ ull shfl_xor_u64(ull v, int m) {
  unsigned lo = __shfl_xor((unsigned)v, m);
  unsigned hi = __shfl_xor((unsigned)(v >> 32), m);
  return ((ull)hi << 32) | lo;
}

__device__ __forceinline__ void st64(ull* p, ull v) {
  __hip_atomic_store(p, v, __ATOMIC_RELAXED, __HIP_MEMORY_SCOPE_AGENT);
}
__device__ __forceinline__ ull ld64(const ull* p) {
  return __hip_atomic_load(p, __ATOMIC_RELAXED, __HIP_MEMORY_SCOPE_AGENT);
}

// ordered-uint encode for float (monotone for all finite floats)
__device__ __forceinline__ unsigned ordenc(float f) {
  unsigned u = __float_as_uint(f);
  return (u >> 31) ? ~u : (u | 0x80000000u);
}

__device__ __forceinline__ unsigned knn_key(float x, float y, float z, float pp,
                                            float sx, float sy, float sz, float s2) {
  float dot = __fmaf_rn(sx, x, __fmaf_rn(sy, y, __fmul_rn(sz, z)));
  float d2 = __fadd_rn(__fsub_rn(s2, __fadd_rn(dot, dot)), pp);
  return ordenc(d2);
}

__device__ __forceinline__ void select_bucket(const unsigned* hist, int nbins,
                                              unsigned krem, unsigned* sres, int lane) {
  const int per = nbins >> 6;
  unsigned local = 0;
  for (int j = 0; j < per; ++j) local += hist[lane * per + j];
  unsigned inc = local;
  for (int off = 1; off < 64; off <<= 1) {
    unsigned v = __shfl_up(inc, off);
    if (lane >= off) inc += v;
  }
  unsigned exc = inc - local;
  if (exc < krem && krem <= inc) {
    unsigned c = exc;
    for (int j = 0; j < per; ++j) {
      unsigned h = hist[lane * per + j];
      if (c + h >= krem) { sres[0] = (unsigned)(lane * per + j); sres[1] = c; break; }
      c += h;
    }
  }
}

// ---- fused: fps (blocks 0..15) + prep+knn workers (16..143), overlapped -----
// kslots[2][16]: {seq:14|dist2:32|~idx:18} parity lines.
// mb[g*16+c] = {coord:32|seq:32}: one 128B line per group, posted at step g.
__global__ void __launch_bounds__(1024) fps_knn_kernel(const float* __restrict__ pc,
    const float* __restrict__ w2, const float* __restrict__ w3,
    unsigned short* __restrict__ w2t, unsigned short* __restrict__ w3t,
    float* __restrict__ sampled_out, int* __restrict__ knn,
    unsigned* __restrict__ cnts, ull* __restrict__ kslots, ull* __restrict__ mb,
    ull* __restrict__ cslots) {
  __shared__ __align__(16) char sbuf[90112];
  __shared__ unsigned sres[2];
  __shared__ unsigned scnt[6];
  __shared__ float mbx[3];
  __shared__ float rs[3][16];
  __shared__ ull wkeyL[16];
  __shared__ float bc[3];
  const int tid = threadIdx.x;
  const int lane = tid & 63, wv = tid >> 6;

  if (blockIdx.x >= FPS_B) {
    // =============== worker role: prep slice, then knn for group g ===========
    const int g = blockIdx.x - FPS_B;
    {  // weight transpose slice (runs during fps)
      int i3 = g * 1024 + tid;
      { int n = i3 >> 7, k = i3 & 127; w3t[i3] = f2bf(w3[k * 1024 + n]); }
      if (g < 8) { int i2 = g * 1024 + tid; int n = i2 >> 6, k = i2 & 63; w2t[i2] = f2bf(w2[k * 128 + n]); }
    }
    unsigned* hist = (unsigned*)sbuf;              // 8 KiB
    unsigned* candk = (unsigned*)(sbuf + 8192);    // 32 KiB
    unsigned* candi = (unsigned*)(sbuf + 40960);   // 32 KiB
    unsigned* candk2 = (unsigned*)(sbuf + 73728);  // 8 KiB
    unsigned* candi2 = (unsigned*)(sbuf + 81920);  // 8 KiB
    for (int i = tid; i < 2048; i += 1024) hist[i] = 0u;
    if (tid < 6) scnt[tid] = 0u;
    if (tid < 3) {  // wait for this group's sampled point (long-interval poll)
      ull v;
      for (;;) {
        v = ld64(&mb[g * 16 + tid]);
        if ((unsigned)v == (unsigned)(g + 1)) break;
        __builtin_amdgcn_s_sleep(64);
      }
      mbx[tid] = __uint_as_float((unsigned)(v >> 32));
    }
    __syncthreads();
    const float sx = mbx[0], sy = mbx[1], sz = mbx[2];
    const float s2 = __fadd_rn(__fadd_rn(__fmul_rn(sx, sx), __fmul_rn(sy, sy)),
                               __fmul_rn(sz, sz));
    const f32x4* xs4 = (const f32x4*)pc;
    const f32x4* ys4 = (const f32x4*)(pc + N_PTS);
    const f32x4* zs4 = (const f32x4*)(pc + 2 * N_PTS);
    // subsample scan: first 16384 points -> rank-160 bucket => threshold T'
    for (int it = 0; it < 4; ++it) {
      int i4 = it * 1024 + tid;
      f32x4 xv = xs4[i4], yv = ys4[i4], zv = zs4[i4];
#pragma unroll
      for (int u = 0; u < 4; ++u) {
        float pp = __fadd_rn(__fadd_rn(__fmul_rn(xv[u], xv[u]), __fmul_rn(yv[u], yv[u])),
                             __fmul_rn(zv[u], zv[u]));
        unsigned k = knn_key(xv[u], yv[u], zv[u], pp, sx, sy, sz, s2);
        atomicAdd(&hist[k >> 21], 1u);
      }
    }
    __syncthreads();
    if (tid < 64) select_bucket(hist, 2048, 160u, sres, lane);
    __syncthreads();
    const unsigned Tp = (sres[0] >= 2047u) ? 0xFFFFFFFFu : ((sres[0] + 1u) << 21);
    __syncthreads();
    // full scan: collect candidates with key < T'
    for (int it = 0; it < 64; ++it) {
      int i4 = it * 1024 + tid;
      f32x4 xv = xs4[i4], yv = ys4[i4], zv = zs4[i4];
#pragma unroll
      for (int u = 0; u < 4; ++u) {
        float pp = __fadd_rn(__fadd_rn(__fmul_rn(xv[u], xv[u]), __fmul_rn(yv[u], yv[u])),
                             __fmul_rn(zv[u], zv[u]));
        unsigned k = knn_key(xv[u], yv[u], zv[u], pp, sx, sy, sz, s2);
        if (k < Tp) {
          unsigned e = atomicAdd(&scnt[0], 1u);
          if (e < 8192u) { candk[e] = k; candi[e] = (unsigned)(i4 * 4 + u); }
        }
      }
    }
    __syncthreads();
    const int m = (int)min(scnt[0], 8192u);
    for (int i = tid; i < 2048; i += 1024) hist[i] = 0u;
    __syncthreads();
    for (int j = tid; j < m; j += 1024) atomicAdd(&hist[candk[j] >> 21], 1u);
    __syncthreads();
    if (tid < 64) select_bucket(hist, 2048, GS, sres, lane);
    __syncthreads();
    const unsigned bA = sres[0];
    unsigned krem = GS - sres[1];
    __syncthreads();
    for (int j = tid; j < m; j += 1024) {
      unsigned k = candk[j], b = k >> 21;
      if (b < bA) {
        unsigned pos = atomicAdd(&scnt[1], 1u);
        knn[g * GS + (int)pos] = (int)candi[j];
      } else if (b == bA) {
        unsigned e = atomicAdd(&scnt[2], 1u);
        if (e < 2048u) { candk2[e] = k; candi2[e] = candi[j]; }
      }
    }
    __syncthreads();
    const int m2 = (int)min(scnt[2], 2048u);
    const int base1 = (int)scnt[1];
    for (int i = tid; i < 2048; i += 1024) hist[i] = 0u;
    __syncthreads();
    for (int j = tid; j < m2; j += 1024) atomicAdd(&hist[(candk2[j] >> 10) & 2047u], 1u);
    __syncthreads();
    if (tid < 64) select_bucket(hist, 2048, krem, sres, lane);
    __syncthreads();
    const unsigned bB = sres[0];
    krem -= sres[1];
    __syncthreads();
    if (tid < 1024) hist[tid] = 0u;
    __syncthreads();
    for (int j = tid; j < m2; j += 1024)
      if (((candk2[j] >> 10) & 2047u) == bB) atomicAdd(&hist[candk2[j] & 1023u], 1u);
    __syncthreads();
    if (tid < 64) select_bucket(hist, 1024, krem, sres, lane);
    __syncthreads();
    const unsigned bC = sres[0];
    krem -= sres[1];
    const unsigned T = (bA << 21) | (bB << 10) | bC;
    __syncthreads();
    for (int j = tid; j < m2; j += 1024) {
      unsigned k = candk2[j];
      if (k < T) {
        unsigned pos = atomicAdd(&scnt[3], 1u);
        knn[g * GS + base1 + (int)pos] = (int)candi2[j];
      } else if (k == T) {
        unsigned e = atomicAdd(&scnt[4], 1u);
        if (e < 2048u) hist[e] = candi2[j];
      }
    }
    __syncthreads();
    if (tid < 64) {
      const int tc = (int)min(scnt[4], 2048u);
      const int base2 = base1 + (int)scnt[3];
      for (int j = 0; j < (int)krem; ++j) {
        int best = 0x7FFFFFFF;
        for (int q = lane; q < tc; q += 64) best = min(best, (int)hist[q]);
        for (int mm = 32; mm; mm >>= 1) best = min(best, __shfl_xor(best, mm));
        for (int q = lane; q < tc; q += 64)
          if ((int)hist[q] == best) hist[q] = 0x7FFFFFFFu;
        if (lane == 0) knn[g * GS + base2 + j] = best;
      }
    }
    return;
  }

  // ===================== FPS role (R15/R16 protocol) =========================
  const int p = blockIdx.x;
  const int gt = p * 1024 + tid;
  const float* xs = pc;
  const float* ys = pc + N_PTS;
  const float* zs = pc + 2 * N_PTS;
  float x[16], y[16], z[16], md[16];
  float sx = 0.f, sy = 0.f, sz = 0.f;
#pragma unroll
  for (int j = 0; j < 16; ++j) {
    int i = gt + j * 16384;
    x[j] = xs[i]; y[j] = ys[i]; z[j] = zs[i];
    sx += x[j]; sy += y[j]; sz += z[j];
  }
#pragma unroll
  for (int m = 32; m; m >>= 1) {
    sx += __shfl_xor(sx, m); sy += __shfl_xor(sy, m); sz += __shfl_xor(sz, m);
  }
  if (lane == 0) { rs[0][wv] = sx; rs[1][wv] = sy; rs[2][wv] = sz; }
  __syncthreads();
  if (tid == 0) {
    float ax = 0.f, ay = 0.f, az = 0.f;
    for (int w = 0; w < 16; ++w) { ax += rs[0][w]; ay += rs[1][w]; az += rs[2][w]; }
    st64(&cslots[0 + p], (ull)__float_as_uint(ax));
    st64(&cslots[16 + p], (ull)__float_as_uint(ay));
    st64(&cslots[32 + p], (ull)__float_as_uint(az));
    __hip_atomic_fetch_add(&cnts[4], 1u, __ATOMIC_RELEASE, __HIP_MEMORY_SCOPE_AGENT);
  }
  if (wv == 0) {
    while (__hip_atomic_load(&cnts[4], __ATOMIC_RELAXED, __HIP_MEMORY_SCOPE_AGENT) < 16u)
      __builtin_amdgcn_s_sleep(1);
    (void)__hip_atomic_load(&cnts[4], __ATOMIC_ACQUIRE, __HIP_MEMORY_SCOPE_AGENT);
    float f = 0.f;
    if (lane < 48) f = __uint_as_float((unsigned)ld64(&cslots[lane]));
    float s = 0.f;
    for (int q = 0; q < 16; ++q) s += __shfl(f, (lane & 48) + q);  // ascending order
    if (lane == 0)  bc[0] = s * (1.f / N_PTS);
    if (lane == 16) bc[1] = s * (1.f / N_PTS);
    if (lane == 32) bc[2] = s * (1.f / N_PTS);
  }
  __syncthreads();
  ull lkey = 0ull;
  {
    float cx = bc[0], cy = bc[1], cz = bc[2];
#pragma unroll
    for (int j = 0; j < 16; ++j) {
      float dx = x[j] - cx, dy = y[j] - cy, dz = z[j] - cz;
      float d = __fmaf_rn(dx, dx, __fmaf_rn(dy, dy, dz * dz));  // squared dist
      md[j] = d;
      unsigned fb = __float_as_uint(d);
      ull k = ((ull)fb << 18) | (ull)(0x3FFFFu ^ (unsigned)(gt + j * 16384));
      if (k > lkey) lkey = k;
    }
  }
  for (int sel = 0; sel < NG; ++sel) {
    const ull seq = (ull)(sel + 1);
    ull rk = lkey;
#pragma unroll
    for (int m = 32; m; m >>= 1) {
      ull o = shfl_xor_u64(rk, m);
      if (o > rk) rk = o;
    }
    if (lane == 0) wkeyL[wv] = rk;
    __syncthreads();
    if (wv == 0) {
      const int pb = (sel & 1) * 16;  // depth-2 parity line
      ull bk = (lane < 16) ? wkeyL[lane] : 0ull;
#pragma unroll
      for (int m = 8; m; m >>= 1) {
        ull o = shfl_xor_u64(bk, m);
        if (o > bk) bk = o;
      }
      if (lane == 0) st64(&kslots[pb + p], (seq << 50) | bk);  // fire-and-forget
      // poll + speculative per-slot coord prefetch
      ull v = 0ull; float c = 0.f;
      bool got = (lane >= 48);
      for (;;) {
        if (!got) {
          v = ld64(&kslots[pb + (lane & 15)]);
          if ((v >> 50) == seq) {
            got = true;
            unsigned idx = 0x3FFFFu ^ (unsigned)(v & 0x3FFFFull);
            c = pc[(lane >> 4) * N_PTS + idx];  // in-flight while others poll
          }
        }
        if (__all((int)got)) break;
      }
      ull gk = v;
      int ws_ = lane & 15;
#pragma unroll
      for (int m = 8; m; m >>= 1) {  // winner within each 16-lane group
        ull o = shfl_xor_u64(gk, m);
        int ow = __shfl_xor(ws_, m);
        if (o > gk) { gk = o; ws_ = ow; }
      }
      if (lane < 48 && (lane & 15) == ws_) {  // 3 lanes: winner's x, y, z
        bc[lane >> 4] = c;
        if (p == 0) {
          sampled_out[sel * 3 + (lane >> 4)] = c;
          st64(&mb[sel * 16 + (lane >> 4)], ((ull)__float_as_uint(c) << 32) | seq);
        }
      }
    }
    __syncthreads();
    {  // fused md-update + next-step candidate (squared metric)
      float wx = bc[0], wy = bc[1], wz = bc[2];
      ull nk = 0ull;
#pragma unroll
      for (int j = 0; j < 16; ++j) {
        float dx = x[j] - wx, dy = y[j] - wy, dz = z[j] - wz;
        float d = __fmaf_rn(dx, dx, __fmaf_rn(dy, dy, dz * dz));
        float m = (sel == 0) ? d : fminf(md[j], d);
        md[j] = m;
        unsigned fb = __float_as_uint(m);
        ull k = ((ull)fb << 18) | (ull)(0x3FFFFu ^ (unsigned)(gt + j * 16384));
        if (k > nk) nk = k;
      }
      lkey = nk;
    }
  }
}

// ---- fused MLP + max-pool; last split-block combines via release/acquire ----
__global__ void __launch_bounds__(256, 2) mlp_kernel(const float* __restrict__ pc,
    const int* __restrict__ knn, const float* __restrict__ w1,
    const unsigned short* __restrict__ w2t, const unsigned short* __restrict__ w3t,
    unsigned* __restrict__ gout, unsigned* __restrict__ gcnt,
    float* __restrict__ out) {
  const int blk = blockIdx.x, g = blk >> 2, split = blk & 3;
  const int tid = threadIdx.x, lane = tid & 63, wv = tid >> 6;
  __shared__ unsigned gmax[1024];
  __shared__ __align__(16) short h1[128 * 72];
  __shared__ __align__(16) short h2[128 * 136];
  __shared__ float cxs[128], cys[128], czs[128];
  __shared__ unsigned lastS;
  for (int i = tid; i < 1024; i += 256) gmax[i] = 0u;
  const float* xs = pc;
  const float* ys = pc + N_PTS;
  const float* zs = pc + 2 * N_PTS;
  const int ch = tid & 63;
  const int pgrp = tid >> 6;
  const float w10 = w1[ch], w11 = w1[64 + ch], w12 = w1[128 + ch];
  const int r0 = (lane >> 4) * 4;
  const int cB = lane & 15;
  const int kB = (lane >> 4) * 8;
  for (int tile = 0; tile < 2; ++tile) {
    __syncthreads();
    if (tid < 128) {
      int i = knn[g * 1024 + split * 256 + tile * 128 + tid];
      cxs[tid] = xs[i]; cys[tid] = ys[i]; czs[tid] = zs[i];
    }
    __syncthreads();
    for (int q = 0; q < 32; ++q) {
      int p = pgrp * 32 + q;
      float v = fmaxf(__fmaf_rn(cxs[p], w10, __fmaf_rn(cys[p], w11, czs[p] * w12)), 0.f);
      h1[p * 72 + ch] = (short)f2bf(v);
    }
    __syncthreads();
    {
      short8 a[2][2];
#pragma unroll
      for (int mt = 0; mt < 2; ++mt)
#pragma unroll
        for (int ks = 0; ks < 2; ++ks)
          a[mt][ks] = *(const short8*)&h1[((2 * wv + mt) * 16 + cB) * 72 + kB + ks * 32];
#pragma unroll
      for (int n0 = 0; n0 < 8; ++n0) {
        short8 bb[2];
#pragma unroll
        for (int ks = 0; ks < 2; ++ks)
          bb[ks] = *(const short8*)&w2t[(n0 * 16 + cB) * 64 + kB + ks * 32];
#pragma unroll
        for (int mt = 0; mt < 2; ++mt) {
          f32x4 acc = {0.f, 0.f, 0.f, 0.f};
          acc = mfma16(a[mt][0], bb[0], acc);
          acc = mfma16(a[mt][1], bb[1], acc);
          int rr = (2 * wv + mt) * 16 + r0;
#pragma unroll
          for (int r = 0; r < 4; ++r)
            h2[(rr + r) * 136 + n0 * 16 + cB] = (short)f2bf(fmaxf(acc[r], 0.f));
        }
      }
    }
    __syncthreads();
    {
      short8 a2[2][4];
#pragma unroll
      for (int mt = 0; mt < 2; ++mt)
#pragma unroll
        for (int ks = 0; ks < 4; ++ks)
          a2[mt][ks] = *(const short8*)&h2[((2 * wv + mt) * 16 + cB) * 136 + kB + ks * 32];
      for (int n0 = 0; n0 < 64; ++n0) {
        short8 b3[4];
#pragma unroll
        for (int ks = 0; ks < 4; ++ks)
          b3[ks] = *(const short8*)&w3t[(n0 * 16 + cB) * 128 + kB + ks * 32];
        f32x4 acc0 = {0.f, 0.f, 0.f, 0.f}, acc1 = {0.f, 0.f, 0.f, 0.f};
#pragma unroll
        for (int ks = 0; ks < 4; ++ks) acc0 = mfma16(a2[0][ks], b3[ks], acc0);
#pragma unroll
        for (int ks = 0; ks < 4; ++ks) acc1 = mfma16(a2[1][ks], b3[ks], acc1);
        float mv = fmaxf(fmaxf(fmaxf(acc0[0], acc0[1]), fmaxf(acc0[2], acc0[3])),
                         fmaxf(fmaxf(acc1[0], acc1[1]), fmaxf(acc1[2], acc1[3])));
        mv = fmaxf(mv, __shfl_xor(mv, 16));
        mv = fmaxf(mv, __shfl_xor(mv, 32));
        if (lane < 16) atomicMax(&gmax[n0 * 16 + lane], ordenc(mv));
      }
    }
  }
  __syncthreads();
  for (int i = tid; i < 1024; i += 256)
    gout[(g * 4 + split) * 1024 + i] = gmax[i];   // plain stores (R16 path)
  __syncthreads();
  if (tid == 0)
    lastS = __hip_atomic_fetch_add(&gcnt[g], 1u, __ATOMIC_ACQ_REL,
                                   __HIP_MEMORY_SCOPE_AGENT);
  __syncthreads();
  if (lastS == 3u) {  // last split: plain loads (post-acquire), combine, decode
    for (int i = tid; i < 1024; i += 256) {
      unsigned mm = gmax[i];  // own split's values already in LDS
#pragma unroll
      for (int s = 0; s < 4; ++s) {
        unsigned v = gout[(g * 4 + s) * 1024 + i];
        if (v > mm) mm = v;
      }
      out[g * 1024 + i] = (mm >> 31) ? __uint_as_float(mm ^ 0x80000000u)
                                     : __uint_as_float(~mm);
    }
  }
}

extern "C" void kernel_launch(void* const* d_in, const int* in_sizes, int n_in,
                              void* d_out, int out_size, void* d_ws, size_t ws_size,
                              hipStream_t stream) {
  (void)in_sizes; (void)n_in; (void)out_size; (void)ws_size;
  const float* pc = (const float*)d_in[0];
  const float* w1 = (const float*)d_in[1];
  const float* w2 = (const float*)d_in[2];
  const float* w3 = (const float*)d_in[3];
  float* out = (float*)d_out;
  char* ws = (char*)d_ws;

  unsigned* cnts = (unsigned*)(ws + 0);        // centroid counter at [4]
  ull* kslots = (ull*)(ws + 128);              // 32 ull = two 128B parity lines
  ull* cslots = (ull*)(ws + 1024);             // 48 ull centroid partials
  ull* mb = (ull*)(ws + 2048);                 // 128 groups x 128B mailbox lines
  unsigned* gcnt = (unsigned*)(ws + 18432);    // 128 group finish counters
  unsigned short* w2t = (unsigned short*)(ws + 24576);           // 16 KiB
  unsigned short* w3t = (unsigned short*)(ws + 24576 + 16384);   // 256 KiB
  int* knn = (int*)(ws + 24576 + 16384 + 262144);                // 512 KiB
  unsigned* gout = (unsigned*)(ws + 24576 + 16384 + 262144 + 524288); // 2 MiB
  float* sampled = out + 131072;

  hipMemsetAsync(ws, 0, 20480, stream);
  fps_knn_kernel<<<FPS_B + NG, 1024, 0, stream>>>(pc, w2, w3, w2t, w3t, sampled,
                                                  knn, cnts, kslots, mb, cslots);
  mlp_kernel<<<NG * 4, 256, 0, stream>>>(pc, knn, w1, w2t, w3t, gout, gcnt, out);
}

// Round 20
// 579.100 us; speedup vs baseline: 1.0240x; 1.0240x over previous
//
#include <hip/hip_runtime.h>

#define N_PTS 262144
#define NG 128
#define GS 1024
#define FPS_B 16

typedef __attribute__((ext_vector_type(8))) short short8;
typedef __attribute__((ext_vector_type(8))) __bf16 bf16x8;
typedef __attribute__((ext_vector_type(4))) float f32x4;
typedef unsigned long long ull;

__device__ __forceinline__ unsigned short f2bf(float f) {
  unsigned u = __float_as_uint(f);
  unsigned r = u + 0x7FFFu + ((u >> 16) & 1u);
  return (unsigned short)(r >> 16);
}

__device__ __forceinline__ f32x4 mfma16(short8 a, short8 b, f32x4 c) {
  return __builtin_amdgcn_mfma_f32_16x16x32_bf16(
      __builtin_bit_cast(bf16x8, a), __builtin_bit_cast(bf16x8, b), c, 0, 0, 0);
}

__device__ __forceinline__ ull shfl_xor_u64(ull v, int m) {
  unsigned lo = __shfl_xor((unsigned)v, m);
  unsigned hi = __shfl_xor((unsigned)(v >> 32), m);
  return ((ull)hi << 32) | lo;
}

__device__ __forceinline__ void st64(ull* p, ull v) {
  __hip_atomic_store(p, v, __ATOMIC_RELAXED, __HIP_MEMORY_SCOPE_AGENT);
}
__device__ __forceinline__ ull ld64(const ull* p) {
  return __hip_atomic_load(p, __ATOMIC_RELAXED, __HIP_MEMORY_SCOPE_AGENT);
}

// ordered-uint encode for float (monotone for all finite floats)
__device__ __forceinline__ unsigned ordenc(float f) {
  unsigned u = __float_as_uint(f);
  return (u >> 31) ? ~u : (u | 0x80000000u);
}

__device__ __forceinline__ unsigned knn_key(float x, float y, float z, float pp,
                                            float sx, float sy, float sz, float s2) {
  float dot = __fmaf_rn(sx, x, __fmaf_rn(sy, y, __fmul_rn(sz, z)));
  float d2 = __fadd_rn(__fsub_rn(s2, __fadd_rn(dot, dot)), pp);
  return ordenc(d2);
}

__device__ __forceinline__ void select_bucket(const unsigned* hist, int nbins,
                                              unsigned krem, unsigned* sres, int lane) {
  const int per = nbins >> 6;
  unsigned local = 0;
  for (int j = 0; j < per; ++j) local += hist[lane * per + j];
  unsigned inc = local;
  for (int off = 1; off < 64; off <<= 1) {
    unsigned v = __shfl_up(inc, off);
    if (lane >= off) inc += v;
  }
  unsigned exc = inc - local;
  if (exc < krem && krem <= inc) {
    unsigned c = exc;
    for (int j = 0; j < per; ++j) {
      unsigned h = hist[lane * per + j];
      if (c + h >= krem) { sres[0] = (unsigned)(lane * per + j); sres[1] = c; break; }
      c += h;
    }
  }
}

// ---- fused: fps (blocks 0..15) + prep+knn workers (16..143), overlapped -----
// kslots[2][16]: {seq:14|dist2:32|~idx:18} parity lines.
// mb[g*16+c] = {coord:32|seq:32}: one 128B line per group, posted at step g.
__global__ void __launch_bounds__(1024) fps_knn_kernel(const float* __restrict__ pc,
    const float* __restrict__ w2, const float* __restrict__ w3,
    unsigned short* __restrict__ w2t, unsigned short* __restrict__ w3t,
    float* __restrict__ sampled_out, int* __restrict__ knn,
    unsigned* __restrict__ cnts, ull* __restrict__ kslots, ull* __restrict__ mb,
    ull* __restrict__ cslots) {
  __shared__ __align__(16) char sbuf[90112];
  __shared__ unsigned sres[2];
  __shared__ unsigned scnt[6];
  __shared__ float mbx[3];
  __shared__ float rs[3][16];
  __shared__ ull wkeyL[16];
  __shared__ float bc[3];
  const int tid = threadIdx.x;
  const int lane = tid & 63, wv = tid >> 6;

  if (blockIdx.x >= FPS_B) {
    // =============== worker role: prep slice, then knn for group g ===========
    const int g = blockIdx.x - FPS_B;
    {  // weight transpose slice (runs during fps)
      int i3 = g * 1024 + tid;
      { int n = i3 >> 7, k = i3 & 127; w3t[i3] = f2bf(w3[k * 1024 + n]); }
      if (g < 8) { int i2 = g * 1024 + tid; int n = i2 >> 6, k = i2 & 63; w2t[i2] = f2bf(w2[k * 128 + n]); }
    }
    unsigned* hist = (unsigned*)sbuf;              // 8 KiB
    unsigned* candk = (unsigned*)(sbuf + 8192);    // 32 KiB
    unsigned* candi = (unsigned*)(sbuf + 40960);   // 32 KiB
    unsigned* candk2 = (unsigned*)(sbuf + 73728);  // 8 KiB
    unsigned* candi2 = (unsigned*)(sbuf + 81920);  // 8 KiB
    for (int i = tid; i < 2048; i += 1024) hist[i] = 0u;
    if (tid < 6) scnt[tid] = 0u;
    if (tid < 3) {  // wait for this group's sampled point (long-interval poll)
      ull v;
      for (;;) {
        v = ld64(&mb[g * 16 + tid]);
        if ((unsigned)v == (unsigned)(g + 1)) break;
        __builtin_amdgcn_s_sleep(64);
      }
      mbx[tid] = __uint_as_float((unsigned)(v >> 32));
    }
    __syncthreads();
    const float sx = mbx[0], sy = mbx[1], sz = mbx[2];
    const float s2 = __fadd_rn(__fadd_rn(__fmul_rn(sx, sx), __fmul_rn(sy, sy)),
                               __fmul_rn(sz, sz));
    const f32x4* xs4 = (const f32x4*)pc;
    const f32x4* ys4 = (const f32x4*)(pc + N_PTS);
    const f32x4* zs4 = (const f32x4*)(pc + 2 * N_PTS);
    // subsample scan: first 16384 points -> rank-160 bucket => threshold T'
    for (int it = 0; it < 4; ++it) {
      int i4 = it * 1024 + tid;
      f32x4 xv = xs4[i4], yv = ys4[i4], zv = zs4[i4];
#pragma unroll
      for (int u = 0; u < 4; ++u) {
        float pp = __fadd_rn(__fadd_rn(__fmul_rn(xv[u], xv[u]), __fmul_rn(yv[u], yv[u])),
                             __fmul_rn(zv[u], zv[u]));
        unsigned k = knn_key(xv[u], yv[u], zv[u], pp, sx, sy, sz, s2);
        atomicAdd(&hist[k >> 21], 1u);
      }
    }
    __syncthreads();
    if (tid < 64) select_bucket(hist, 2048, 160u, sres, lane);
    __syncthreads();
    const unsigned Tp = (sres[0] >= 2047u) ? 0xFFFFFFFFu : ((sres[0] + 1u) << 21);
    __syncthreads();
    // full scan: collect candidates with key < T' (exact superset of top-1024 w.h.p.)
    for (int it = 0; it < 64; ++it) {
      int i4 = it * 1024 + tid;
      f32x4 xv = xs4[i4], yv = ys4[i4], zv = zs4[i4];
#pragma unroll
      for (int u = 0; u < 4; ++u) {
        float pp = __fadd_rn(__fadd_rn(__fmul_rn(xv[u], xv[u]), __fmul_rn(yv[u], yv[u])),
                             __fmul_rn(zv[u], zv[u]));
        unsigned k = knn_key(xv[u], yv[u], zv[u], pp, sx, sy, sz, s2);
        if (k < Tp) {
          unsigned e = atomicAdd(&scnt[0], 1u);
          if (e < 8192u) { candk[e] = k; candi[e] = (unsigned)(i4 * 4 + u); }
        }
      }
    }
    __syncthreads();
    const int m = (int)min(scnt[0], 8192u);
    for (int i = tid; i < 2048; i += 1024) hist[i] = 0u;
    __syncthreads();
    for (int j = tid; j < m; j += 1024) atomicAdd(&hist[candk[j] >> 21], 1u);
    __syncthreads();
    if (tid < 64) select_bucket(hist, 2048, GS, sres, lane);
    __syncthreads();
    const unsigned bA = sres[0];
    unsigned krem = GS - sres[1];
    __syncthreads();
    for (int j = tid; j < m; j += 1024) {
      unsigned k = candk[j], b = k >> 21;
      if (b < bA) {
        unsigned pos = atomicAdd(&scnt[1], 1u);
        knn[g * GS + (int)pos] = (int)candi[j];
      } else if (b == bA) {
        unsigned e = atomicAdd(&scnt[2], 1u);
        if (e < 2048u) { candk2[e] = k; candi2[e] = candi[j]; }
      }
    }
    __syncthreads();
    const int m2 = (int)min(scnt[2], 2048u);
    const int base1 = (int)scnt[1];
    for (int i = tid; i < 2048; i += 1024) hist[i] = 0u;
    __syncthreads();
    for (int j = tid; j < m2; j += 1024) atomicAdd(&hist[(candk2[j] >> 10) & 2047u], 1u);
    __syncthreads();
    if (tid < 64) select_bucket(hist, 2048, krem, sres, lane);
    __syncthreads();
    const unsigned bB = sres[0];
    krem -= sres[1];
    __syncthreads();
    if (tid < 1024) hist[tid] = 0u;
    __syncthreads();
    for (int j = tid; j < m2; j += 1024)
      if (((candk2[j] >> 10) & 2047u) == bB) atomicAdd(&hist[candk2[j] & 1023u], 1u);
    __syncthreads();
    if (tid < 64) select_bucket(hist, 1024, krem, sres, lane);
    __syncthreads();
    const unsigned bC = sres[0];
    krem -= sres[1];
    const unsigned T = (bA << 21) | (bB << 10) | bC;
    __syncthreads();
    for (int j = tid; j < m2; j += 1024) {
      unsigned k = candk2[j];
      if (k < T) {
        unsigned pos = atomicAdd(&scnt[3], 1u);
        knn[g * GS + base1 + (int)pos] = (int)candi2[j];
      } else if (k == T) {
        unsigned e = atomicAdd(&scnt[4], 1u);
        if (e < 2048u) hist[e] = candi2[j];
      }
    }
    __syncthreads();
    if (tid < 64) {
      const int tc = (int)min(scnt[4], 2048u);
      const int base2 = base1 + (int)scnt[3];
      for (int j = 0; j < (int)krem; ++j) {
        int best = 0x7FFFFFFF;
        for (int q = lane; q < tc; q += 64) best = min(best, (int)hist[q]);
        for (int mm = 32; mm; mm >>= 1) best = min(best, __shfl_xor(best, mm));
        for (int q = lane; q < tc; q += 64)
          if ((int)hist[q] == best) hist[q] = 0x7FFFFFFFu;
        if (lane == 0) knn[g * GS + base2 + j] = best;
      }
    }
    return;
  }

  // ===================== FPS role (R15 protocol + mailbox posts) =============
  const int p = blockIdx.x;
  const int gt = p * 1024 + tid;
  const float* xs = pc;
  const float* ys = pc + N_PTS;
  const float* zs = pc + 2 * N_PTS;
  float x[16], y[16], z[16], md[16];
  float sx = 0.f, sy = 0.f, sz = 0.f;
#pragma unroll
  for (int j = 0; j < 16; ++j) {
    int i = gt + j * 16384;
    x[j] = xs[i]; y[j] = ys[i]; z[j] = zs[i];
    sx += x[j]; sy += y[j]; sz += z[j];
  }
#pragma unroll
  for (int m = 32; m; m >>= 1) {
    sx += __shfl_xor(sx, m); sy += __shfl_xor(sy, m); sz += __shfl_xor(sz, m);
  }
  if (lane == 0) { rs[0][wv] = sx; rs[1][wv] = sy; rs[2][wv] = sz; }
  __syncthreads();
  if (tid == 0) {
    float ax = 0.f, ay = 0.f, az = 0.f;
    for (int w = 0; w < 16; ++w) { ax += rs[0][w]; ay += rs[1][w]; az += rs[2][w]; }
    st64(&cslots[0 + p], (ull)__float_as_uint(ax));
    st64(&cslots[16 + p], (ull)__float_as_uint(ay));
    st64(&cslots[32 + p], (ull)__float_as_uint(az));
    __hip_atomic_fetch_add(&cnts[4], 1u, __ATOMIC_RELEASE, __HIP_MEMORY_SCOPE_AGENT);
  }
  if (wv == 0) {
    while (__hip_atomic_load(&cnts[4], __ATOMIC_RELAXED, __HIP_MEMORY_SCOPE_AGENT) < 16u)
      __builtin_amdgcn_s_sleep(1);
    (void)__hip_atomic_load(&cnts[4], __ATOMIC_ACQUIRE, __HIP_MEMORY_SCOPE_AGENT);
    float f = 0.f;
    if (lane < 48) f = __uint_as_float((unsigned)ld64(&cslots[lane]));
    float s = 0.f;
    for (int q = 0; q < 16; ++q) s += __shfl(f, (lane & 48) + q);  // ascending order
    if (lane == 0)  bc[0] = s * (1.f / N_PTS);
    if (lane == 16) bc[1] = s * (1.f / N_PTS);
    if (lane == 32) bc[2] = s * (1.f / N_PTS);
  }
  __syncthreads();
  ull lkey = 0ull;
  {
    float cx = bc[0], cy = bc[1], cz = bc[2];
#pragma unroll
    for (int j = 0; j < 16; ++j) {
      float dx = x[j] - cx, dy = y[j] - cy, dz = z[j] - cz;
      float d = __fmaf_rn(dx, dx, __fmaf_rn(dy, dy, dz * dz));  // squared dist
      md[j] = d;
      unsigned fb = __float_as_uint(d);
      ull k = ((ull)fb << 18) | (ull)(0x3FFFFu ^ (unsigned)(gt + j * 16384));
      if (k > lkey) lkey = k;
    }
  }
  for (int sel = 0; sel < NG; ++sel) {
    const ull seq = (ull)(sel + 1);
    ull rk = lkey;
#pragma unroll
    for (int m = 32; m; m >>= 1) {
      ull o = shfl_xor_u64(rk, m);
      if (o > rk) rk = o;
    }
    if (lane == 0) wkeyL[wv] = rk;
    __syncthreads();
    if (wv == 0) {
      const int pb = (sel & 1) * 16;  // depth-2 parity line
      ull bk = (lane < 16) ? wkeyL[lane] : 0ull;
#pragma unroll
      for (int m = 8; m; m >>= 1) {
        ull o = shfl_xor_u64(bk, m);
        if (o > bk) bk = o;
      }
      if (lane == 0) st64(&kslots[pb + p], (seq << 50) | bk);  // fire-and-forget
      // poll + speculative per-slot coord prefetch
      ull v = 0ull; float c = 0.f;
      bool got = (lane >= 48);
      for (;;) {
        if (!got) {
          v = ld64(&kslots[pb + (lane & 15)]);
          if ((v >> 50) == seq) {
            got = true;
            unsigned idx = 0x3FFFFu ^ (unsigned)(v & 0x3FFFFull);
            c = pc[(lane >> 4) * N_PTS + idx];  // in-flight while others poll
          }
        }
        if (__all((int)got)) break;
      }
      ull gk = v;
      int ws_ = lane & 15;
#pragma unroll
      for (int m = 8; m; m >>= 1) {  // winner within each 16-lane group
        ull o = shfl_xor_u64(gk, m);
        int ow = __shfl_xor(ws_, m);
        if (o > gk) { gk = o; ws_ = ow; }
      }
      if (lane < 48 && (lane & 15) == ws_) {  // 3 lanes: winner's x, y, z
        bc[lane >> 4] = c;
        if (p == 0) {
          sampled_out[sel * 3 + (lane >> 4)] = c;
          st64(&mb[sel * 16 + (lane >> 4)], ((ull)__float_as_uint(c) << 32) | seq);
        }
      }
    }
    __syncthreads();
    {  // fused md-update + next-step candidate (squared metric)
      float wx = bc[0], wy = bc[1], wz = bc[2];
      ull nk = 0ull;
#pragma unroll
      for (int j = 0; j < 16; ++j) {
        float dx = x[j] - wx, dy = y[j] - wy, dz = z[j] - wz;
        float d = __fmaf_rn(dx, dx, __fmaf_rn(dy, dy, dz * dz));
        float m = (sel == 0) ? d : fminf(md[j], d);
        md[j] = m;
        unsigned fb = __float_as_uint(m);
        ull k = ((ull)fb << 18) | (ull)(0x3FFFFu ^ (unsigned)(gt + j * 16384));
        if (k > nk) nk = k;
      }
      lkey = nk;
    }
  }
}

// ---------------- fused MLP + max-pool, bf16 MFMA ----------------------------
__global__ void __launch_bounds__(256, 2) mlp_kernel(const float* __restrict__ pc,
    const int* __restrict__ knn, const float* __restrict__ w1,
    const unsigned short* __restrict__ w2t, const unsigned short* __restrict__ w3t,
    unsigned* __restrict__ gout) {
  const int blk = blockIdx.x, g = blk >> 2, split = blk & 3;
  const int tid = threadIdx.x, lane = tid & 63, wv = tid >> 6;
  __shared__ unsigned gmax[1024];
  __shared__ __align__(16) short h1[128 * 72];
  __shared__ __align__(16) short h2[128 * 136];
  __shared__ float cxs[128], cys[128], czs[128];
  for (int i = tid; i < 1024; i += 256) gmax[i] = 0u;
  const float* xs = pc;
  const float* ys = pc + N_PTS;
  const float* zs = pc + 2 * N_PTS;
  const int ch = tid & 63;
  const int pgrp = tid >> 6;
  const float w10 = w1[ch], w11 = w1[64 + ch], w12 = w1[128 + ch];
  const int r0 = (lane >> 4) * 4;
  const int cB = lane & 15;
  const int kB = (lane >> 4) * 8;
  for (int tile = 0; tile < 2; ++tile) {
    __syncthreads();
    if (tid < 128) {
      int i = knn[g * 1024 + split * 256 + tile * 128 + tid];
      cxs[tid] = xs[i]; cys[tid] = ys[i]; czs[tid] = zs[i];
    }
    __syncthreads();
    for (int q = 0; q < 32; ++q) {
      int p = pgrp * 32 + q;
      float v = fmaxf(__fmaf_rn(cxs[p], w10, __fmaf_rn(cys[p], w11, czs[p] * w12)), 0.f);
      h1[p * 72 + ch] = (short)f2bf(v);
    }
    __syncthreads();
    {
      short8 a[2][2];
#pragma unroll
      for (int mt = 0; mt < 2; ++mt)
#pragma unroll
        for (int ks = 0; ks < 2; ++ks)
          a[mt][ks] = *(const short8*)&h1[((2 * wv + mt) * 16 + cB) * 72 + kB + ks * 32];
#pragma unroll
      for (int n0 = 0; n0 < 8; ++n0) {
        short8 bb[2];
#pragma unroll
        for (int ks = 0; ks < 2; ++ks)
          bb[ks] = *(const short8*)&w2t[(n0 * 16 + cB) * 64 + kB + ks * 32];
#pragma unroll
        for (int mt = 0; mt < 2; ++mt) {
          f32x4 acc = {0.f, 0.f, 0.f, 0.f};
          acc = mfma16(a[mt][0], bb[0], acc);
          acc = mfma16(a[mt][1], bb[1], acc);
          int rr = (2 * wv + mt) * 16 + r0;
#pragma unroll
          for (int r = 0; r < 4; ++r)
            h2[(rr + r) * 136 + n0 * 16 + cB] = (short)f2bf(fmaxf(acc[r], 0.f));
        }
      }
    }
    __syncthreads();
    {
      short8 a2[2][4];
#pragma unroll
      for (int mt = 0; mt < 2; ++mt)
#pragma unroll
        for (int ks = 0; ks < 4; ++ks)
          a2[mt][ks] = *(const short8*)&h2[((2 * wv + mt) * 16 + cB) * 136 + kB + ks * 32];
      for (int n0 = 0; n0 < 64; ++n0) {
        short8 b3[4];
#pragma unroll
        for (int ks = 0; ks < 4; ++ks)
          b3[ks] = *(const short8*)&w3t[(n0 * 16 + cB) * 128 + kB + ks * 32];
        f32x4 acc0 = {0.f, 0.f, 0.f, 0.f}, acc1 = {0.f, 0.f, 0.f, 0.f};
#pragma unroll
        for (int ks = 0; ks < 4; ++ks) acc0 = mfma16(a2[0][ks], b3[ks], acc0);
#pragma unroll
        for (int ks = 0; ks < 4; ++ks) acc1 = mfma16(a2[1][ks], b3[ks], acc1);
        float mv = fmaxf(fmaxf(fmaxf(acc0[0], acc0[1]), fmaxf(acc0[2], acc0[3])),
                         fmaxf(fmaxf(acc1[0], acc1[1]), fmaxf(acc1[2], acc1[3])));
        mv = fmaxf(mv, __shfl_xor(mv, 16));
        mv = fmaxf(mv, __shfl_xor(mv, 32));
        if (lane < 16) atomicMax(&gmax[n0 * 16 + lane], ordenc(mv));
      }
    }
  }
  __syncthreads();
  for (int i = tid; i < 1024; i += 256)
    gout[(g * 4 + split) * 1024 + i] = gmax[i];
}

// ---------------- combine split partials -> d_out ----------------------------
__global__ void __launch_bounds__(256) combine_kernel(const unsigned* __restrict__ gm,
                                                      float* __restrict__ out) {
  int c = blockIdx.x * 256 + threadIdx.x;
  int g = c >> 10, chn = c & 1023;
  unsigned m = 0u;
#pragma unroll
  for (int s = 0; s < 4; ++s) {
    unsigned v = gm[(g * 4 + s) * 1024 + chn];
    if (v > m) m = v;
  }
  out[c] = (m >> 31) ? __uint_as_float(m ^ 0x80000000u) : __uint_as_float(~m);
}

extern "C" void kernel_launch(void* const* d_in, const int* in_sizes, int n_in,
                              void* d_out, int out_size, void* d_ws, size_t ws_size,
                              hipStream_t stream) {
  (void)in_sizes; (void)n_in; (void)out_size; (void)ws_size;
  const float* pc = (const float*)d_in[0];
  const float* w1 = (const float*)d_in[1];
  const float* w2 = (const float*)d_in[2];
  const float* w3 = (const float*)d_in[3];
  float* out = (float*)d_out;
  char* ws = (char*)d_ws;

  unsigned* cnts = (unsigned*)(ws + 0);        // centroid counter at [4]
  ull* kslots = (ull*)(ws + 128);              // 32 ull = two 128B parity lines
  ull* cslots = (ull*)(ws + 1024);             // 48 ull centroid partials
  ull* mb = (ull*)(ws + 2048);                 // 128 groups x 128B mailbox lines
  unsigned short* w2t = (unsigned short*)(ws + 24576);           // 16 KiB
  unsigned short* w3t = (unsigned short*)(ws + 24576 + 16384);   // 256 KiB
  int* knn = (int*)(ws + 24576 + 16384 + 262144);                // 512 KiB
  unsigned* gout = (unsigned*)(ws + 24576 + 16384 + 262144 + 524288); // 2 MiB
  float* sampled = out + 131072;

  hipMemsetAsync(ws, 0, 20480, stream);
  fps_knn_kernel<<<FPS_B + NG, 1024, 0, stream>>>(pc, w2, w3, w2t, w3t, sampled,
                                                  knn, cnts, kslots, mb, cslots);
  mlp_kernel<<<NG * 4, 256, 0, stream>>>(pc, knn, w1, w2t, w3t, gout);
  combine_kernel<<<512, 256, 0, stream>>>(gout, out);
}